// Round 5
// baseline (173.506 us; speedup 1.0000x reference)
//
#include <hip/hip_runtime.h>
#include <math.h>

typedef float v2f __attribute__((ext_vector_type(2)));

#define NSUP 512
#define DLAT 128
#define DHID 512
#define DIN  64
#define BR   16
#define NTILE 256   // 4096 / BR

// Force a pointer into a VGPR so the uniformity pass cannot scalarize loads
// through it: keeps broadcast reads on the (deeply-pipelined) vector pipe.
__device__ __forceinline__ const float* launder(const float* p) {
    unsigned long long v = (unsigned long long)p;
    asm volatile("" : "+v"(v));
    return (const float*)v;
}
__device__ __forceinline__ const float4* launder4(const float4* p) {
    unsigned long long v = (unsigned long long)p;
    asm volatile("" : "+v"(v));
    return (const float4*)v;
}

// ---------------- prep: transposes + packs + support trig + norms ----------------
__global__ __launch_bounds__(512) void prep_kernel(
    const float* __restrict__ x, const float* __restrict__ W1, const float* __restrict__ W2,
    const float* __restrict__ support,
    float* __restrict__ W1T, float* __restrict__ W2T, float* __restrict__ xpack,
    float* __restrict__ scS, float* __restrict__ scC, float* __restrict__ scN,
    float* __restrict__ sn2)
{
    int idx = blockIdx.x * 512 + threadIdx.x;          // 512 x 512 = 262144
    {   // xpack[t][k][r] = x[t*16+r][k]   (writes coalesced)
        int t = idx >> 10, rem = idx & 1023, k = rem >> 4, r = rem & 15;
        xpack[idx] = x[((t << 4) | r) * DIN + k];
    }
    if (idx < DHID * DIN) {                 // W1 [512][64] -> W1T [64][512]
        int c = idx / DIN, k = idx % DIN;
        W1T[k * DHID + c] = W1[idx];
    }
    if (idx < DLAT * DHID) {
        int j = idx / DHID, k = idx % DHID;             // W2 -> W2T
        W2T[k * DLAT + j] = W2[idx];
        int s = idx & (NSUP - 1), i = idx >> 9;         // planar scd[i][s], coalesced
        float v = support[s * DLAT + i];
        scS[idx] = v;
        scC[idx] = cosf(0.5f * v);
        scN[idx] = sinf(0.5f * v);
    }
    if (idx < NSUP) {                       // ||s||^2 via float4
        const float4* sp = (const float4*)(support + idx * DLAT);
        float acc = 0.f;
        #pragma unroll 8
        for (int i4 = 0; i4 < DLAT / 4; i4++) {
            float4 v = sp[i4];
            acc = fmaf(v.x, v.x, fmaf(v.y, v.y, fmaf(v.z, v.z, fmaf(v.w, v.w, acc))));
        }
        sn2[idx] = acc;
    }
}

// ---------------- GEMM1: h = tanh(x @ W1^T + b1) ----------------
// grid 256 x 512. thread c owns hidden col c (16 rows); LDS-staged coalesced store.
__global__ __launch_bounds__(512) void gemm1_kernel(
    const float* __restrict__ W1T, const float* __restrict__ b1,
    const float* __restrict__ xpack, float* __restrict__ hpack)
{
    __shared__ float sh[DHID][17];                           // 34.8 KB
    const int t = blockIdx.x;
    const int c = threadIdx.x;
    const float4* xb = launder4((const float4*)(xpack + t * (DIN * BR)));  // VMEM broadcast

    v2f acc[8];
    #pragma unroll
    for (int q = 0; q < 8; q++) acc[q] = (v2f)(0.f);

    #pragma unroll 4
    for (int k = 0; k < DIN; k++) {
        float w = W1T[k * DHID + c];
        v2f wv = {w, w};
        float4 X0 = xb[k * 4 + 0], X1 = xb[k * 4 + 1], X2 = xb[k * 4 + 2], X3 = xb[k * 4 + 3];
        acc[0] = __builtin_elementwise_fma((v2f){X0.x, X0.y}, wv, acc[0]);
        acc[1] = __builtin_elementwise_fma((v2f){X0.z, X0.w}, wv, acc[1]);
        acc[2] = __builtin_elementwise_fma((v2f){X1.x, X1.y}, wv, acc[2]);
        acc[3] = __builtin_elementwise_fma((v2f){X1.z, X1.w}, wv, acc[3]);
        acc[4] = __builtin_elementwise_fma((v2f){X2.x, X2.y}, wv, acc[4]);
        acc[5] = __builtin_elementwise_fma((v2f){X2.z, X2.w}, wv, acc[5]);
        acc[6] = __builtin_elementwise_fma((v2f){X3.x, X3.y}, wv, acc[6]);
        acc[7] = __builtin_elementwise_fma((v2f){X3.z, X3.w}, wv, acc[7]);
    }
    float bb = b1[c];
    #pragma unroll
    for (int q = 0; q < 8; q++) {
        sh[c][2 * q]     = tanhf(acc[q].x + bb);
        sh[c][2 * q + 1] = tanhf(acc[q].y + bb);
    }
    __syncthreads();
    // coalesced store: 2048 float4 per tile, 4 per thread
    float4* hp = (float4*)(hpack + t * (DHID * BR));
    #pragma unroll
    for (int w = threadIdx.x; w < DHID * BR / 4; w += 512) {
        int cc = w >> 2, r0 = (w & 3) * 4;
        hp[w] = make_float4(sh[cc][r0], sh[cc][r0 + 1], sh[cc][r0 + 2], sh[cc][r0 + 3]);
    }
}

// ---------------- GEMM2: latent + trig -> rowpack [t][i][48]={l16|a16|b16} ----------------
// grid 256 x 1024. thread: latent col j = tid&127, k-group g = tid>>7 (64 k each)
__global__ __launch_bounds__(1024) void gemm2_kernel(
    const float* __restrict__ W2T, const float* __restrict__ b2,
    const float* __restrict__ hpack, float4* __restrict__ rowpack, float* __restrict__ ln2s)
{
    __shared__ float part[8][DLAT][17];    // 69632 B
    __shared__ float tbuf[DLAT][49];       // 25088 B transpose buffer
    __shared__ float l2red[16][2];

    const int t = blockIdx.x;
    const int j = threadIdx.x & (DLAT - 1);
    const int g = __builtin_amdgcn_readfirstlane(threadIdx.x >> 7);   // wave-uniform
    const float4* hb = launder4((const float4*)(hpack + t * (DHID * BR)));  // VMEM broadcast

    v2f acc[8];
    #pragma unroll
    for (int q = 0; q < 8; q++) acc[q] = (v2f)(0.f);

    #pragma unroll 4
    for (int kk = 0; kk < 64; kk++) {
        int k = g * 64 + kk;
        float w = W2T[k * DLAT + j];
        v2f wv = {w, w};
        float4 H0 = hb[k * 4 + 0], H1 = hb[k * 4 + 1], H2 = hb[k * 4 + 2], H3 = hb[k * 4 + 3];
        acc[0] = __builtin_elementwise_fma((v2f){H0.x, H0.y}, wv, acc[0]);
        acc[1] = __builtin_elementwise_fma((v2f){H0.z, H0.w}, wv, acc[1]);
        acc[2] = __builtin_elementwise_fma((v2f){H1.x, H1.y}, wv, acc[2]);
        acc[3] = __builtin_elementwise_fma((v2f){H1.z, H1.w}, wv, acc[3]);
        acc[4] = __builtin_elementwise_fma((v2f){H2.x, H2.y}, wv, acc[4]);
        acc[5] = __builtin_elementwise_fma((v2f){H2.z, H2.w}, wv, acc[5]);
        acc[6] = __builtin_elementwise_fma((v2f){H3.x, H3.y}, wv, acc[6]);
        acc[7] = __builtin_elementwise_fma((v2f){H3.z, H3.w}, wv, acc[7]);
    }
    #pragma unroll
    for (int q = 0; q < 8; q++) {
        part[g][j][2 * q]     = acc[q].x;
        part[g][j][2 * q + 1] = acc[q].y;
    }
    __syncthreads();

    const int rp = g;                                   // row-pair 0..7
    float s0 = 0.f, s1 = 0.f;
    #pragma unroll
    for (int g2 = 0; g2 < 8; g2++) {
        s0 += part[g2][j][2 * rp];
        s1 += part[g2][j][2 * rp + 1];
    }
    float bb = b2[j];
    float l0 = s0 + bb, l1 = s1 + bb;

    tbuf[j][2 * rp]          = l0;
    tbuf[j][2 * rp + 1]      = l1;
    tbuf[j][16 + 2 * rp]     = cosf(0.5f * l0);
    tbuf[j][16 + 2 * rp + 1] = cosf(0.5f * l1);
    tbuf[j][32 + 2 * rp]     = sinf(0.5f * l0);
    tbuf[j][32 + 2 * rp + 1] = sinf(0.5f * l1);

    // ||l||^2 per row
    const int wv = threadIdx.x >> 6;
    float v0 = l0 * l0, v1 = l1 * l1;
    for (int off = 32; off; off >>= 1) { v0 += __shfl_down(v0, off); v1 += __shfl_down(v1, off); }
    if ((threadIdx.x & 63) == 0) { l2red[wv][0] = v0; l2red[wv][1] = v1; }
    __syncthreads();

    if (threadIdx.x < BR) {
        int r = threadIdx.x, p = r >> 1, sel = r & 1;
        ln2s[t * BR + r] = l2red[2 * p][sel] + l2red[2 * p + 1][sel];
    }
    // coalesced rowpack store: 128*48 floats = 1536 float4 per tile
    for (int w = threadIdx.x; w < DLAT * 48 / 4; w += 1024) {
        int i = w / 12, off = (w % 12) * 4;
        rowpack[t * 1536 + w] = make_float4(tbuf[i][off], tbuf[i][off + 1],
                                            tbuf[i][off + 2], tbuf[i][off + 3]);
    }
}

// ---------------- stage B: kernels + weighted support reduction ----------------
// grid 256 x 1024 (16 waves). half = i-range; wave&7 picks support group.
__global__ __launch_bounds__(1024) void kernelB(
    const float* __restrict__ scS, const float* __restrict__ scC, const float* __restrict__ scN,
    const float* __restrict__ sn2, const float* __restrict__ wts,
    const float* __restrict__ rowpack, const float* __restrict__ ln2s, float* __restrict__ out)
{
    __shared__ float c01[NSUP][17];     // half0 -> partials for rows 8..15 (8 dot | 8 prod)
    __shared__ float c10[NSUP][17];     // half1 -> partials for rows 0..7
    __shared__ float redw[16][8];

    const int t    = blockIdx.x;
    const int lane = threadIdx.x & 63;
    const int wvu  = __builtin_amdgcn_readfirstlane(threadIdx.x >> 6);  // wave-uniform
    const int half = wvu >> 3;
    const int s    = ((wvu & 7) << 6) | lane;
    const int i0   = half * 64;

    const float4* rpb = launder4((const float4*)(rowpack + t * (DLAT * 48)));  // VMEM bcast
    const int sbase = i0 * NSUP + s;

    v2f dot[8], prod[8];
    #pragma unroll
    for (int q = 0; q < 8; q++) { dot[q] = (v2f)(0.f); prod[q] = (v2f)(1.f); }

    #pragma unroll 2
    for (int ii = 0; ii < 64; ii++) {
        int si = sbase + ii * NSUP;
        float sv = scS[si], cv = scC[si], nv = scN[si];   // per-lane, coalesced
        v2f svv = {sv, sv}, cvv = {cv, cv}, nvv = {nv, nv};
        int b4 = (i0 + ii) * 12;
        float4 L0 = rpb[b4 + 0], L1 = rpb[b4 + 1],  L2 = rpb[b4 + 2],  L3 = rpb[b4 + 3];
        float4 A0 = rpb[b4 + 4], A1 = rpb[b4 + 5],  A2 = rpb[b4 + 6],  A3 = rpb[b4 + 7];
        float4 B0 = rpb[b4 + 8], B1 = rpb[b4 + 9],  B2 = rpb[b4 + 10], B3 = rpb[b4 + 11];
        #define STEPQ(q, lv, av, bv) { \
            dot[q] = __builtin_elementwise_fma(lv, svv, dot[q]); \
            v2f tt = __builtin_elementwise_fma(av, cvv, (bv) * nvv); \
            prod[q] = prod[q] * tt; }
        STEPQ(0, ((v2f){L0.x, L0.y}), ((v2f){A0.x, A0.y}), ((v2f){B0.x, B0.y}))
        STEPQ(1, ((v2f){L0.z, L0.w}), ((v2f){A0.z, A0.w}), ((v2f){B0.z, B0.w}))
        STEPQ(2, ((v2f){L1.x, L1.y}), ((v2f){A1.x, A1.y}), ((v2f){B1.x, B1.y}))
        STEPQ(3, ((v2f){L1.z, L1.w}), ((v2f){A1.z, A1.w}), ((v2f){B1.z, B1.w}))
        STEPQ(4, ((v2f){L2.x, L2.y}), ((v2f){A2.x, A2.y}), ((v2f){B2.x, B2.y}))
        STEPQ(5, ((v2f){L2.z, L2.w}), ((v2f){A2.z, A2.w}), ((v2f){B2.z, B2.w}))
        STEPQ(6, ((v2f){L3.x, L3.y}), ((v2f){A3.x, A3.y}), ((v2f){B3.x, B3.y}))
        STEPQ(7, ((v2f){L3.z, L3.w}), ((v2f){A3.z, A3.w}), ((v2f){B3.z, B3.w}))
        #undef STEPQ
    }

    // exchange: each half publishes the OTHER half's row-range partials
    if (half == 0) {
        #pragma unroll
        for (int q = 4; q < 8; q++) {
            c01[s][2 * (q - 4)]         = dot[q].x;
            c01[s][2 * (q - 4) + 1]     = dot[q].y;
            c01[s][8 + 2 * (q - 4)]     = prod[q].x;
            c01[s][8 + 2 * (q - 4) + 1] = prod[q].y;
        }
    } else {
        #pragma unroll
        for (int q = 0; q < 4; q++) {
            c10[s][2 * q]         = dot[q].x;
            c10[s][2 * q + 1]     = dot[q].y;
            c10[s][8 + 2 * q]     = prod[q].x;
            c10[s][8 + 2 * q + 1] = prod[q].y;
        }
    }
    __syncthreads();

    // combine own 8 rows
    float dfull[8], pfull[8];
    if (half == 0) {
        #pragma unroll
        for (int q = 0; q < 4; q++) {
            dfull[2 * q]     = dot[q].x + c10[s][2 * q];
            dfull[2 * q + 1] = dot[q].y + c10[s][2 * q + 1];
            pfull[2 * q]     = prod[q].x * c10[s][8 + 2 * q];
            pfull[2 * q + 1] = prod[q].y * c10[s][8 + 2 * q + 1];
        }
    } else {
        #pragma unroll
        for (int q = 4; q < 8; q++) {
            dfull[2 * (q - 4)]     = dot[q].x + c01[s][2 * (q - 4)];
            dfull[2 * (q - 4) + 1] = dot[q].y + c01[s][2 * (q - 4) + 1];
            pfull[2 * (q - 4)]     = prod[q].x * c01[s][8 + 2 * (q - 4)];
            pfull[2 * (q - 4) + 1] = prod[q].y * c01[s][8 + 2 * (q - 4) + 1];
        }
    }

    float sn  = sn2[s];
    float wgt = wts[s];
    const float* lr = launder(ln2s + ((t << 4) | (half << 3)));
    #pragma unroll
    for (int rr = 0; rr < 8; rr++) {
        float sq = lr[rr] + sn - 2.f * dfull[rr];
        float kc = __expf(-sq);
        float p  = pfull[rr];
        float v  = (0.5f * kc + 0.5f * (p * p)) * wgt;
        for (int off = 32; off; off >>= 1) v += __shfl_down(v, off);
        if (lane == 0) redw[wvu][rr] = v;
    }
    __syncthreads();
    if (threadIdx.x < BR) {
        int h = threadIdx.x >> 3, rr = threadIdx.x & 7;
        float o = 0.f;
        #pragma unroll
        for (int w = 0; w < 8; w++) o += redw[h * 8 + w][rr];
        out[t * BR + h * 8 + rr] = o;
    }
}

// ---------------- launch ----------------
extern "C" void kernel_launch(void* const* d_in, const int* in_sizes, int n_in,
                              void* d_out, int out_size, void* d_ws, size_t ws_size,
                              hipStream_t stream) {
    const float* x       = (const float*)d_in[0];
    const float* W1      = (const float*)d_in[1];
    const float* b1      = (const float*)d_in[2];
    const float* W2      = (const float*)d_in[3];
    const float* b2      = (const float*)d_in[4];
    const float* support = (const float*)d_in[5];
    const float* wts     = (const float*)d_in[6];
    float* out = (float*)d_out;

    float* ws      = (float*)d_ws;
    float* W1T     = ws;                        // 32768
    float* W2T     = W1T + 32768;               // 65536
    float* xpack   = W2T + 65536;               // 262144
    float* hpack   = xpack + 262144;            // 2097152   (16B-aligned offset)
    float* rowpack = hpack + 2097152;           // 1572864   (16B-aligned offset)
    float* ln2s    = rowpack + 1572864;         // 4096
    float* sn2     = ln2s + 4096;               // 512
    float* scS     = sn2 + 512;                 // 65536
    float* scC     = scS + 65536;               // 65536
    float* scN     = scC + 65536;               // 65536

    prep_kernel <<<512,  512, 0, stream>>>(x, W1, W2, support, W1T, W2T, xpack,
                                           scS, scC, scN, sn2);
    gemm1_kernel<<<NTILE, 512, 0, stream>>>(W1T, b1, xpack, hpack);
    gemm2_kernel<<<NTILE, 1024, 0, stream>>>(W2T, b2, hpack, (float4*)rowpack, ln2s);
    kernelB     <<<NTILE, 1024, 0, stream>>>(scS, scC, scN, sn2, wts, rowpack, ln2s, out);
}

// Round 6
// 73.366 us; speedup vs baseline: 2.3649x; 2.3649x over previous
//
#include <hip/hip_runtime.h>
#include <math.h>

typedef float v2f __attribute__((ext_vector_type(2)));

#define NSUP 512
#define DLAT 128
#define DHID 512
#define DIN  64
#define BR   16
#define NTILE 256   // 4096 / BR

// ---------------- prep: transposes + packs + support trig + norms ----------------
__global__ __launch_bounds__(512) void prep_kernel(
    const float* __restrict__ x, const float* __restrict__ W1, const float* __restrict__ W2,
    const float* __restrict__ support,
    float* __restrict__ W1T, float* __restrict__ W2T, float* __restrict__ xpack,
    float4* __restrict__ scd, float* __restrict__ sn2)
{
    int idx = blockIdx.x * 512 + threadIdx.x;          // 512 x 512 = 262144
    {   // xpack[t][k][r] = x[t*16+r][k]   (writes coalesced)
        int t = idx >> 10, rem = idx & 1023, k = rem >> 4, r = rem & 15;
        xpack[idx] = x[((t << 4) | r) * DIN + k];
    }
    if (idx < DHID * DIN) {                 // W1 [512][64] -> W1T [64][512]
        int c = idx / DIN, k = idx % DIN;
        W1T[k * DHID + c] = W1[idx];
    }
    if (idx < DLAT * DHID) {
        int j = idx / DHID, k = idx % DHID;             // W2 -> W2T
        W2T[k * DLAT + j] = W2[idx];
        int s = idx & (NSUP - 1), i = idx >> 9;         // scd[i][s], writes coalesced
        float v = support[s * DLAT + i];
        scd[i * NSUP + s] = make_float4(v, cosf(0.5f * v), sinf(0.5f * v), 0.f);
    }
    if (idx < NSUP) {                       // ||s||^2 via float4
        const float4* sp = (const float4*)(support + idx * DLAT);
        float acc = 0.f;
        #pragma unroll 8
        for (int i4 = 0; i4 < DLAT / 4; i4++) {
            float4 v = sp[i4];
            acc = fmaf(v.x, v.x, fmaf(v.y, v.y, fmaf(v.z, v.z, fmaf(v.w, v.w, acc))));
        }
        sn2[idx] = acc;
    }
}

// ---------------- GEMM1: h = tanh(x @ W1^T + b1)  (round-4 form, s_load path) ----------------
__global__ __launch_bounds__(512) void gemm1_kernel(
    const float* __restrict__ W1T, const float* __restrict__ b1,
    const float* __restrict__ xpack, float* __restrict__ hpack)
{
    __shared__ float sh[DHID][17];                           // 34.8 KB
    const int t = blockIdx.x;
    const int c = threadIdx.x;
    const float* __restrict__ xr = xpack + t * (DIN * BR);   // uniform base -> s_load

    v2f acc[8];
    #pragma unroll
    for (int q = 0; q < 8; q++) acc[q] = (v2f)(0.f);

    for (int k = 0; k < DIN; k++) {
        float w = W1T[k * DHID + c];
        v2f wv = {w, w};
        const float* xk = xr + k * BR;                       // uniform -> s_load_dwordx16
        #pragma unroll
        for (int q = 0; q < 8; q++) {
            v2f xv = {xk[2 * q], xk[2 * q + 1]};
            acc[q] = __builtin_elementwise_fma(xv, wv, acc[q]);
        }
    }
    float bb = b1[c];
    #pragma unroll
    for (int q = 0; q < 8; q++) {
        sh[c][2 * q]     = tanhf(acc[q].x + bb);
        sh[c][2 * q + 1] = tanhf(acc[q].y + bb);
    }
    __syncthreads();
    float4* hp = (float4*)(hpack + t * (DHID * BR));
    #pragma unroll
    for (int w = threadIdx.x; w < DHID * BR / 4; w += 512) {
        int cc = w >> 2, r0 = (w & 3) * 4;
        hp[w] = make_float4(sh[cc][r0], sh[cc][r0 + 1], sh[cc][r0 + 2], sh[cc][r0 + 3]);
    }
}

// ---------------- GEMM2: latent + trig -> rowpack [t][i][48]={l16|a16|b16} ----------------
__global__ __launch_bounds__(1024) void gemm2_kernel(
    const float* __restrict__ W2T, const float* __restrict__ b2,
    const float* __restrict__ hpack, float4* __restrict__ rowpack, float* __restrict__ ln2s)
{
    __shared__ float part[8][DLAT][17];    // 69632 B
    __shared__ float tbuf[DLAT][49];       // 25088 B transpose buffer
    __shared__ float l2red[16][2];

    const int t = blockIdx.x;
    const int j = threadIdx.x & (DLAT - 1);
    const int g = __builtin_amdgcn_readfirstlane(threadIdx.x >> 7);   // wave-uniform
    const float* __restrict__ hrow = hpack + t * (DHID * BR);

    v2f acc[8];
    #pragma unroll
    for (int q = 0; q < 8; q++) acc[q] = (v2f)(0.f);

    for (int kk = 0; kk < 64; kk++) {
        int k = g * 64 + kk;
        float w = W2T[k * DLAT + j];
        v2f wv = {w, w};
        const float* hk = hrow + k * BR;               // uniform -> s_load_dwordx16
        #pragma unroll
        for (int q = 0; q < 8; q++) {
            v2f hv = {hk[2 * q], hk[2 * q + 1]};
            acc[q] = __builtin_elementwise_fma(hv, wv, acc[q]);
        }
    }
    #pragma unroll
    for (int q = 0; q < 8; q++) {
        part[g][j][2 * q]     = acc[q].x;
        part[g][j][2 * q + 1] = acc[q].y;
    }
    __syncthreads();

    const int rp = g;                                   // row-pair 0..7
    float s0 = 0.f, s1 = 0.f;
    #pragma unroll
    for (int g2 = 0; g2 < 8; g2++) {
        s0 += part[g2][j][2 * rp];
        s1 += part[g2][j][2 * rp + 1];
    }
    float bb = b2[j];
    float l0 = s0 + bb, l1 = s1 + bb;

    tbuf[j][2 * rp]          = l0;
    tbuf[j][2 * rp + 1]      = l1;
    tbuf[j][16 + 2 * rp]     = cosf(0.5f * l0);
    tbuf[j][16 + 2 * rp + 1] = cosf(0.5f * l1);
    tbuf[j][32 + 2 * rp]     = sinf(0.5f * l0);
    tbuf[j][32 + 2 * rp + 1] = sinf(0.5f * l1);

    // ||l||^2 per row
    const int wv = threadIdx.x >> 6;
    float v0 = l0 * l0, v1 = l1 * l1;
    for (int off = 32; off; off >>= 1) { v0 += __shfl_down(v0, off); v1 += __shfl_down(v1, off); }
    if ((threadIdx.x & 63) == 0) { l2red[wv][0] = v0; l2red[wv][1] = v1; }
    __syncthreads();

    if (threadIdx.x < BR) {
        int r = threadIdx.x, p = r >> 1, sel = r & 1;
        ln2s[t * BR + r] = l2red[2 * p][sel] + l2red[2 * p + 1][sel];
    }
    // coalesced rowpack store: 128*48 floats = 1536 float4 per tile
    for (int w = threadIdx.x; w < DLAT * 48 / 4; w += 1024) {
        int i = w / 12, off = (w % 12) * 4;
        rowpack[t * 1536 + w] = make_float4(tbuf[i][off], tbuf[i][off + 1],
                                            tbuf[i][off + 2], tbuf[i][off + 3]);
    }
}

// ---------------- stage B: 4-sup x 4-row register tile per lane ----------------
// grid 256 x 512 (8 waves). wave = (row-quad rq = wv&3, sup-half sh = wv>>2).
// lane owns sups { sh*256 + lane + 64k, k<4 } x rows { rq*4 .. rq*4+3 }.
__global__ __launch_bounds__(512) void kernelB(
    const float4* __restrict__ scd, const float* __restrict__ sn2,
    const float* __restrict__ wts, const float4* __restrict__ rowpack4,
    const float* __restrict__ ln2s, float* __restrict__ out)
{
    __shared__ float tile[DLAT * 48];   // 24 KB: [i][ l16 | a16 | b16 ]
    __shared__ float redw[8][4];

    const int t    = blockIdx.x;
    const int tid  = threadIdx.x;
    const int lane = tid & 63;
    const int wv   = __builtin_amdgcn_readfirstlane(tid >> 6);
    const int rq   = wv & 3;
    const int sh   = wv >> 2;
    const int s0   = sh * 256 + lane;

    // ---- stage rowpack tile: 1536 float4, coalesced ----
    {
        const float4* src = rowpack4 + t * 1536;
        float4* dst = (float4*)tile;
        #pragma unroll
        for (int k = 0; k < 3; k++) dst[tid + k * 512] = src[tid + k * 512];
    }
    __syncthreads();

    v2f dot[4][2], prod[4][2];
    #pragma unroll
    for (int k = 0; k < 4; k++) {
        dot[k][0] = (v2f)(0.f); dot[k][1] = (v2f)(0.f);
        prod[k][0] = (v2f)(1.f); prod[k][1] = (v2f)(1.f);
    }

    const float4* sb = scd + s0;        // + i*512 + k*64

    #pragma unroll 2
    for (int i = 0; i < DLAT; i++) {
        const float* tp = tile + i * 48 + rq * 4;
        float4 lq = *(const float4*)(tp);          // rows rq*4..+3: latent
        float4 aq = *(const float4*)(tp + 16);     // cos(l/2)
        float4 bq = *(const float4*)(tp + 32);     // sin(l/2)
        v2f l01 = {lq.x, lq.y}, l23 = {lq.z, lq.w};
        v2f a01 = {aq.x, aq.y}, a23 = {aq.z, aq.w};
        v2f b01 = {bq.x, bq.y}, b23 = {bq.z, bq.w};
        const float4* sbi = sb + i * NSUP;
        #pragma unroll
        for (int k = 0; k < 4; k++) {
            float4 sc = sbi[k * 64];               // {s, cos(s/2), sin(s/2), 0}
            v2f sv = {sc.x, sc.x}, cv = {sc.y, sc.y}, nv = {sc.z, sc.z};
            dot[k][0] = __builtin_elementwise_fma(l01, sv, dot[k][0]);
            dot[k][1] = __builtin_elementwise_fma(l23, sv, dot[k][1]);
            v2f t0 = __builtin_elementwise_fma(a01, cv, b01 * nv);
            v2f t1 = __builtin_elementwise_fma(a23, cv, b23 * nv);
            prod[k][0] = prod[k][0] * t0;
            prod[k][1] = prod[k][1] * t1;
        }
    }

    // ---- epilogue: kernels, weight, reduce ----
    const float* lr = ln2s + t * BR + rq * 4;      // 4 row norms (uniform-ish, tiny)
    float l2[4] = {lr[0], lr[1], lr[2], lr[3]};
    float rowacc[4] = {0.f, 0.f, 0.f, 0.f};
    #pragma unroll
    for (int k = 0; k < 4; k++) {
        int s = s0 + k * 64;
        float snk = sn2[s];
        float wk  = wts[s];
        #pragma unroll
        for (int rp = 0; rp < 2; rp++) {
            float d0 = dot[k][rp].x, d1 = dot[k][rp].y;
            float p0 = prod[k][rp].x, p1 = prod[k][rp].y;
            int r0 = rp * 2;
            float sq0 = l2[r0]     + snk - 2.f * d0;
            float sq1 = l2[r0 + 1] + snk - 2.f * d1;
            rowacc[r0]     += (0.5f * __expf(-sq0) + 0.5f * (p0 * p0)) * wk;
            rowacc[r0 + 1] += (0.5f * __expf(-sq1) + 0.5f * (p1 * p1)) * wk;
        }
    }
    #pragma unroll
    for (int j = 0; j < 4; j++) {
        float v = rowacc[j];
        for (int off = 32; off; off >>= 1) v += __shfl_down(v, off);
        if (lane == 0) redw[wv][j] = v;
    }
    __syncthreads();
    if (tid < BR) {
        int q = tid >> 2, j = tid & 3;             // row = q*4 + j
        out[t * BR + q * 4 + j] = redw[q][j] + redw[4 + q][j];
    }
}

// ---------------- launch ----------------
extern "C" void kernel_launch(void* const* d_in, const int* in_sizes, int n_in,
                              void* d_out, int out_size, void* d_ws, size_t ws_size,
                              hipStream_t stream) {
    const float* x       = (const float*)d_in[0];
    const float* W1      = (const float*)d_in[1];
    const float* b1      = (const float*)d_in[2];
    const float* W2      = (const float*)d_in[3];
    const float* b2      = (const float*)d_in[4];
    const float* support = (const float*)d_in[5];
    const float* wts     = (const float*)d_in[6];
    float* out = (float*)d_out;

    float* ws      = (float*)d_ws;
    float* W1T     = ws;                        // 32768
    float* W2T     = W1T + 32768;               // 65536
    float* xpack   = W2T + 65536;               // 262144
    float* hpack   = xpack + 262144;            // 2097152   (16B-aligned offset)
    float* rowpack = hpack + 2097152;           // 1572864   (16B-aligned offset)
    float* ln2s    = rowpack + 1572864;         // 4096
    float* sn2     = ln2s + 4096;               // 512
    float4* scd    = (float4*)(sn2 + 512);      // 65536 float4 (16B-aligned offset)

    prep_kernel <<<512,  512, 0, stream>>>(x, W1, W2, support, W1T, W2T, xpack, scd, sn2);
    gemm1_kernel<<<NTILE, 512, 0, stream>>>(W1T, b1, xpack, hpack);
    gemm2_kernel<<<NTILE, 1024, 0, stream>>>(W2T, b2, hpack, (float4*)rowpack, ln2s);
    kernelB     <<<NTILE, 512, 0, stream>>>(scd, sn2, wts, (const float4*)rowpack, ln2s, out);
}